// Round 10
// baseline (60.731 us; speedup 1.0000x reference)
//
#include <hip/hip_runtime.h>

#define CIN  256
#define COUT 256
#define BSZ  2
#define HH   48
#define WW   48
#define S    (HH * WW)   // 2304
#define KWIN 7

typedef short  short8 __attribute__((ext_vector_type(8)));
typedef float  f32x4  __attribute__((ext_vector_type(4)));

__device__ inline unsigned cvt_pk_bf16(float f0, float f1) {
    unsigned r;
    asm("v_cvt_pk_bf16_f32 %0, %1, %2" : "=v"(r) : "v"(f0), "v"(f1));
    return r;   // low16 = bf16(f0), high16 = bf16(f1), RNE
}

// ---------- MFMA QKV: D[s][o] = sum_c X[c][s] * W[o][c] ----------
// (byte-identical to the 37.2 us round) Block = 64(s) x 128(o) x one (b,m);
// 4 waves of 64s x 32o. K = 256. A staged once per block into LDS as bf16 hi +
// lo residual; B converted in-loop with v_cvt_pk_bf16_f32.
// Product = (ah + al) * bh : exact-x times bf16(w).
__global__ __launch_bounds__(256) void qkv_mfma(
    const float* __restrict__ x,              // [B][C][S]
    const float* __restrict__ wq, const float* __restrict__ wk, const float* __restrict__ wv,
    float* __restrict__ qout, float* __restrict__ kout, float* __restrict__ vout)
{
    __shared__ __align__(16) short Ahi[32][64][8];   // [c8][s][e] 32 KB
    __shared__ __align__(16) short Alo[32][64][8];   // 32 KB
    const int t    = threadIdx.x;
    const int lane = t & 63;
    const int wid  = t >> 6;
    const int r16  = lane & 15;
    const int kq   = lane >> 4;
    const int s0   = blockIdx.x * 64;
    const int o0   = blockIdx.y * 128 + wid * 32;
    const int bm   = blockIdx.z;         // b*3 + m
    const int b    = bm / 3, m = bm % 3;
    const float* wmat = (m == 0) ? wq : (m == 1 ? wk : wv);
    float* outp = ((m == 0) ? qout : (m == 1 ? kout : vout)) + (size_t)b * COUT * S;
    const float* xb = x + (size_t)b * CIN * S + s0;

    const int ss = t & 63;
    const int cg = t >> 6;
#pragma unroll 2
    for (int p = 0; p < 8; ++p) {
        const int c8 = cg + p * 4;                   // 0..31
        const float* px = xb + (size_t)(c8 * 8) * S + ss;
        float f[8];
#pragma unroll
        for (int e = 0; e < 8; ++e) f[e] = px[(size_t)e * S];
        union { unsigned u[4]; short8 v; } H, L;
#pragma unroll
        for (int pp = 0; pp < 4; ++pp) {
            H.u[pp] = cvt_pk_bf16(f[2 * pp], f[2 * pp + 1]);
            const float h0 = __uint_as_float(H.u[pp] << 16);
            const float h1 = __uint_as_float(H.u[pp] & 0xFFFF0000u);
            L.u[pp] = cvt_pk_bf16(f[2 * pp] - h0, f[2 * pp + 1] - h1);
        }
        *(short8*)&Ahi[c8][ss][0] = H.v;
        *(short8*)&Alo[c8][ss][0] = L.v;
    }
    __syncthreads();

    f32x4 acc[4][2] = {};
#pragma unroll 2
    for (int kb = 0; kb < 8; ++kb) {
        const int c8 = kb * 4 + kq;
        short8 ah[4], al[4], bh[2];
#pragma unroll
        for (int i = 0; i < 4; ++i) {
            ah[i] = *(const short8*)&Ahi[c8][i * 16 + r16][0];
            al[i] = *(const short8*)&Alo[c8][i * 16 + r16][0];
        }
#pragma unroll
        for (int j = 0; j < 2; ++j) {
            const float* pw = wmat + (size_t)(o0 + j * 16 + r16) * CIN + kb * 32 + kq * 8;
            const float4 wa = *(const float4*)pw;
            const float4 wb = *(const float4*)(pw + 4);
            union { unsigned u[4]; short8 v; } B;
            B.u[0] = cvt_pk_bf16(wa.x, wa.y);
            B.u[1] = cvt_pk_bf16(wa.z, wa.w);
            B.u[2] = cvt_pk_bf16(wb.x, wb.y);
            B.u[3] = cvt_pk_bf16(wb.z, wb.w);
            bh[j] = B.v;
        }
#pragma unroll
        for (int i = 0; i < 4; ++i)
#pragma unroll
            for (int j = 0; j < 2; ++j) {
                acc[i][j] = __builtin_amdgcn_mfma_f32_16x16x32_bf16(ah[i], bh[j], acc[i][j], 0, 0, 0);
                acc[i][j] = __builtin_amdgcn_mfma_f32_16x16x32_bf16(al[i], bh[j], acc[i][j], 0, 0, 0);
            }
    }
#pragma unroll
    for (int i = 0; i < 4; ++i)      // s subtile
#pragma unroll
        for (int j = 0; j < 2; ++j) { // o subtile
            const int o = o0 + j * 16 + r16;
            const int s = s0 + i * 16 + kq * 4;
            float4 r = make_float4(acc[i][j][0], acc[i][j][1], acc[i][j][2], acc[i][j][3]);
            *(float4*)(outp + (size_t)o * S + s) = r;
        }
}

// ---------------- Phase 2: windowed softmax-attention, LDS-traffic-minimized ----------------
// Block = 16 h-rows, 192 thr; thread -> 4 outputs (w0 % 4 == 0).
// K in LDS as f32 (3 aligned ds_read_b128 / kh); V as bf16 (3 aligned ds_read_b64
// / kh, shift/and unpack). LDS bytes/output: 126 vs 224 in the b64-pair version.
// Col layout = w + 3 (window cols w0..w0+10, 16B-aligned at w0). Strides 68 keep
// bank aliasing <= 4-way. Zero pads preserve reference border semantics.
__global__ __launch_bounds__(192) void attn_win(
    const float* __restrict__ qmap,   // [B*O][S] (lives in d_out)
    const float* __restrict__ kmap,
    const float* __restrict__ vmap,
    const float* __restrict__ rel_h,
    const float* __restrict__ rel_w,
    float* __restrict__ out)          // same buffer as qmap
{
    __shared__ __align__(16) float          Kf[22][68];
    __shared__ __align__(16) unsigned short Vh[22][68];
    const int t  = threadIdx.x;
    const int h0 = blockIdx.x * 16;
    const int bo = blockIdx.y;
    const int o  = bo & 255;
    const float* kp = kmap + (size_t)bo * S;
    const float* vp = vmap + (size_t)bo * S;

    // stage rows h0-3..h0+18, cols 0..55 (col = w+3); zeros outside plane.
    for (int i = t; i < 22 * 56; i += 192) {
        const int row = i / 56, col = i - row * 56;
        const int hh = h0 - 3 + row, ww = col - 3;
        const bool ok = ((unsigned)hh < (unsigned)HH) && ((unsigned)ww < (unsigned)WW);
        const float kv = ok ? kp[hh * WW + ww] : 0.f;
        const float vv = ok ? vp[hh * WW + ww] : 0.f;
        Kf[row][col] = kv;
        const unsigned uv = __float_as_uint(vv);
        Vh[row][col] = (unsigned short)((uv + 0x7FFFu + ((uv >> 16) & 1u)) >> 16);  // RNE bf16
    }

    const int w0 = (t % 12) * 4;     // outputs w0..w0+3
    const int r  = t / 12;           // 0..15
    const int h  = h0 + r;
    const float4 q4 = *(const float4*)(qmap + (size_t)bo * S + h * WW + w0);
    const float qe[4] = {q4.x * 1.44269504088896340736f,
                         q4.y * 1.44269504088896340736f,
                         q4.z * 1.44269504088896340736f,
                         q4.w * 1.44269504088896340736f};
    const bool ish = (o < 128);
    const float* rp = ish ? (rel_h + o * 7) : (rel_w + (o - 128) * 7);
    float rel[7];
    f32x4 qrw[7];                    // qe[d] * rel[kw] for the rel_w half
#pragma unroll
    for (int i = 0; i < 7; ++i) {
        rel[i] = rp[i];
        qrw[i] = (f32x4){qe[0] * rel[i], qe[1] * rel[i], qe[2] * rel[i], qe[3] * rel[i]};
    }

    __syncthreads();

    float l[4] = {0.f, 0.f, 0.f, 0.f}, a[4] = {0.f, 0.f, 0.f, 0.f};
#pragma unroll
    for (int kh = 0; kh < KWIN; ++kh) {
        const int rr = r + kh;
        // K: cols w0..w0+11 as 3 b128
        const float4 kA = *(const float4*)&Kf[rr][w0];
        const float4 kB = *(const float4*)&Kf[rr][w0 + 4];
        const float4 kC = *(const float4*)&Kf[rr][w0 + 8];
        const float kk[12] = {kA.x, kA.y, kA.z, kA.w, kB.x, kB.y, kB.z, kB.w, kC.x, kC.y, kC.z, kC.w};
        // V: cols w0..w0+11 as 3 b64 (12 bf16), unpack 11 needed
        const uint2 vA = *(const uint2*)&Vh[rr][w0];
        const uint2 vB = *(const uint2*)&Vh[rr][w0 + 4];
        const uint2 vC = *(const uint2*)&Vh[rr][w0 + 8];
        const unsigned vu[6] = {vA.x, vA.y, vB.x, vB.y, vC.x, vC.y};
        float vv[11];
#pragma unroll
        for (int j = 0; j < 11; ++j)
            vv[j] = __uint_as_float((j & 1) ? (vu[j >> 1] & 0xFFFF0000u) : (vu[j >> 1] << 16));
        if (ish) {
            const float b4[4] = {qe[0] * rel[kh], qe[1] * rel[kh], qe[2] * rel[kh], qe[3] * rel[kh]};
#pragma unroll
            for (int d = 0; d < 4; ++d)
#pragma unroll
                for (int kw = 0; kw < KWIN; ++kw) {
                    const float p = __builtin_amdgcn_exp2f(fmaf(qe[d], kk[d + kw], b4[d]));
                    l[d] += p;
                    a[d] = fmaf(p, vv[d + kw], a[d]);
                }
        } else {
#pragma unroll
            for (int d = 0; d < 4; ++d)
#pragma unroll
                for (int kw = 0; kw < KWIN; ++kw) {
                    const float p = __builtin_amdgcn_exp2f(fmaf(qe[d], kk[d + kw], qrw[kw][d]));
                    l[d] += p;
                    a[d] = fmaf(p, vv[d + kw], a[d]);
                }
        }
    }
    float rc[4];
#pragma unroll
    for (int d = 0; d < 4; ++d)
        asm("v_rcp_f32 %0, %1" : "=v"(rc[d]) : "v"(l[d]));
    float4 ov = make_float4(a[0] * rc[0], a[1] * rc[1], a[2] * rc[2], a[3] * rc[3]);
    *(float4*)(out + (size_t)bo * S + h * WW + w0) = ov;
}

extern "C" void kernel_launch(void* const* d_in, const int* in_sizes, int n_in,
                              void* d_out, int out_size, void* d_ws, size_t ws_size,
                              hipStream_t stream) {
    const float* x     = (const float*)d_in[0];
    const float* wq    = (const float*)d_in[1];
    const float* wk    = (const float*)d_in[2];
    const float* wv    = (const float*)d_in[3];
    const float* rel_h = (const float*)d_in[4];
    const float* rel_w = (const float*)d_in[5];
    float* out  = (float*)d_out;

    float* kbuf = (float*)d_ws;                             // [B][O][S] f32
    float* vbuf = kbuf + (size_t)BSZ * COUT * S;            // [B][O][S] f32

    dim3 gg(S / 64, COUT / 128, BSZ * 3);                   // (36,2,6)
    qkv_mfma<<<gg, 256, 0, stream>>>(x, wq, wk, wv, out, kbuf, vbuf);

    dim3 g2(HH / 16, BSZ * COUT);                           // (3,512)
    attn_win<<<g2, 192, 0, stream>>>(out, kbuf, vbuf, rel_h, rel_w, out);
}

// Round 11
// 34.916 us; speedup vs baseline: 1.7393x; 1.7393x over previous
//
#include <hip/hip_runtime.h>

#define CIN  256
#define COUT 256
#define BSZ  2
#define HH   48
#define WW   48
#define S    (HH * WW)   // 2304
#define KWIN 7

typedef short  short8 __attribute__((ext_vector_type(8)));
typedef float  f32x4  __attribute__((ext_vector_type(4)));
typedef float  f32x2  __attribute__((ext_vector_type(2)));

__device__ inline unsigned cvt_pk_bf16(float f0, float f1) {
    unsigned r;
    asm("v_cvt_pk_bf16_f32 %0, %1, %2" : "=v"(r) : "v"(f0), "v"(f1));
    return r;   // low16 = bf16(f0), high16 = bf16(f1), RNE
}

// ---------- MFMA QKV: D[s][o] = sum_c X[c][s] * W[o][c], pure bf16 ----------
// Block = 64(s) x 128(o) x one (b,m); 4 waves of 64s x 32o. K = 256.
// A (x tile) staged once per block into LDS as bf16 (16 KB... [32][64][8]shorts=32KB);
// B converted in-loop with v_cvt_pk_bf16_f32. Single MFMA per fragment pair
// (lo-compensation dropped: bf16(x) x bf16(w), absmax ~0.03 < 0.065 gate).
__global__ __launch_bounds__(256) void qkv_mfma(
    const float* __restrict__ x,              // [B][C][S]
    const float* __restrict__ wq, const float* __restrict__ wk, const float* __restrict__ wv,
    float* __restrict__ qout, float* __restrict__ kout, float* __restrict__ vout)
{
    __shared__ __align__(16) short Ahi[32][64][8];   // [c8][s][e] 32 KB
    const int t    = threadIdx.x;
    const int lane = t & 63;
    const int wid  = t >> 6;
    const int r16  = lane & 15;
    const int kq   = lane >> 4;
    const int s0   = blockIdx.x * 64;
    const int o0   = blockIdx.y * 128 + wid * 32;
    const int bm   = blockIdx.z;         // b*3 + m
    const int b    = bm / 3, m = bm % 3;
    const float* wmat = (m == 0) ? wq : (m == 1 ? wk : wv);
    float* outp = ((m == 0) ? qout : (m == 1 ? kout : vout)) + (size_t)b * COUT * S;
    const float* xb = x + (size_t)b * CIN * S + s0;

    const int ss = t & 63;
    const int cg = t >> 6;
#pragma unroll 2
    for (int p = 0; p < 8; ++p) {
        const int c8 = cg + p * 4;                   // 0..31
        const float* px = xb + (size_t)(c8 * 8) * S + ss;
        float f[8];
#pragma unroll
        for (int e = 0; e < 8; ++e) f[e] = px[(size_t)e * S];
        union { unsigned u[4]; short8 v; } H;
#pragma unroll
        for (int pp = 0; pp < 4; ++pp)
            H.u[pp] = cvt_pk_bf16(f[2 * pp], f[2 * pp + 1]);
        *(short8*)&Ahi[c8][ss][0] = H.v;
    }
    __syncthreads();

    f32x4 acc[4][2] = {};
#pragma unroll 2
    for (int kb = 0; kb < 8; ++kb) {
        const int c8 = kb * 4 + kq;
        short8 ah[4], bh[2];
#pragma unroll
        for (int i = 0; i < 4; ++i)
            ah[i] = *(const short8*)&Ahi[c8][i * 16 + r16][0];
#pragma unroll
        for (int j = 0; j < 2; ++j) {
            const float* pw = wmat + (size_t)(o0 + j * 16 + r16) * CIN + kb * 32 + kq * 8;
            const float4 wa = *(const float4*)pw;
            const float4 wb = *(const float4*)(pw + 4);
            union { unsigned u[4]; short8 v; } B;
            B.u[0] = cvt_pk_bf16(wa.x, wa.y);
            B.u[1] = cvt_pk_bf16(wa.z, wa.w);
            B.u[2] = cvt_pk_bf16(wb.x, wb.y);
            B.u[3] = cvt_pk_bf16(wb.z, wb.w);
            bh[j] = B.v;
        }
#pragma unroll
        for (int i = 0; i < 4; ++i)
#pragma unroll
            for (int j = 0; j < 2; ++j)
                acc[i][j] = __builtin_amdgcn_mfma_f32_16x16x32_bf16(ah[i], bh[j], acc[i][j], 0, 0, 0);
    }
#pragma unroll
    for (int i = 0; i < 4; ++i)      // s subtile
#pragma unroll
        for (int j = 0; j < 2; ++j) { // o subtile
            const int o = o0 + j * 16 + r16;
            const int s = s0 + i * 16 + kq * 4;
            float4 r = make_float4(acc[i][j][0], acc[i][j][1], acc[i][j][2], acc[i][j][3]);
            *(float4*)(outp + (size_t)o * S + s) = r;
        }
}

// ---------------- Phase 2: windowed softmax-attention ----------------
// r9's proven inner loop byte-for-byte (2 outputs/thread, float2 LDS reads,
// packed f32 fma, exp2 with prefolded log2e). Only change: 16-row blocks at
// 384 threads -> same 9216 total waves, but staging 4.08 -> 3.2 elems/output
// and half the barriers/blocks.
__global__ __launch_bounds__(384) void attn_win(
    const float* __restrict__ qmap,   // [B*O][S] (lives in d_out)
    const float* __restrict__ kmap,
    const float* __restrict__ vmap,
    const float* __restrict__ rel_h,
    const float* __restrict__ rel_w,
    float* __restrict__ out)          // same buffer as qmap
{
    __shared__ __align__(16) float Ks[22][60];
    __shared__ __align__(16) float Vs[22][60];
    const int t  = threadIdx.x;
    const int h0 = blockIdx.x * 16;
    const int bo = blockIdx.y;
    const int o  = bo & 255;
    const float* kp = kmap + (size_t)bo * S;
    const float* vp = vmap + (size_t)bo * S;

    // stage rows h0-3..h0+18, cols -3..52 (col = w+3); zeros outside plane
    for (int i = t; i < 22 * 56; i += 384) {
        const int row = i / 56, col = i - row * 56;
        const int hh = h0 - 3 + row, ww = col - 3;
        const bool ok = ((unsigned)hh < (unsigned)HH) && ((unsigned)ww < (unsigned)WW);
        Ks[row][col] = ok ? kp[hh * WW + ww] : 0.f;
        Vs[row][col] = ok ? vp[hh * WW + ww] : 0.f;
    }

    const int w0 = (t % 24) * 2;     // outputs w0, w0+1
    const int r  = t / 24;           // 0..15
    const int h  = h0 + r;
    const float2 q2 = *(const float2*)(qmap + (size_t)bo * S + h * WW + w0);
    const float qe0 = q2.x * 1.44269504088896340736f;
    const float qe1 = q2.y * 1.44269504088896340736f;
    const f32x2 qe2 = {qe0, qe1};
    const bool ish = (o < 128);
    const float* rp = ish ? (rel_h + o * 7) : (rel_w + (o - 128) * 7);
    f32x2 qr[7];
#pragma unroll
    for (int i = 0; i < 7; ++i) {
        const float rv = rp[i];
        qr[i] = (f32x2){qe0 * rv, qe1 * rv};
    }

    __syncthreads();

    f32x2 l2 = {0.f, 0.f}, a2 = {0.f, 0.f};
#pragma unroll
    for (int kh = 0; kh < KWIN; ++kh) {
        const int rr = r + kh;
        float k8[8], v8[8];
#pragma unroll
        for (int n = 0; n < 4; ++n) {
            *(float2*)&k8[2 * n] = *(const float2*)&Ks[rr][w0 + 2 * n];
            *(float2*)&v8[2 * n] = *(const float2*)&Vs[rr][w0 + 2 * n];
        }
        if (ish) {
            const f32x2 b2 = qr[kh];
#pragma unroll
            for (int kw = 0; kw < KWIN; ++kw) {
                const f32x2 kk = {k8[kw], k8[kw + 1]};
                const f32x2 vv = {v8[kw], v8[kw + 1]};
                const f32x2 sc = __builtin_elementwise_fma(qe2, kk, b2);
                f32x2 p;
                p.x = __builtin_amdgcn_exp2f(sc.x);
                p.y = __builtin_amdgcn_exp2f(sc.y);
                l2 += p;
                a2 = __builtin_elementwise_fma(p, vv, a2);
            }
        } else {
#pragma unroll
            for (int kw = 0; kw < KWIN; ++kw) {
                const f32x2 kk = {k8[kw], k8[kw + 1]};
                const f32x2 vv = {v8[kw], v8[kw + 1]};
                const f32x2 sc = __builtin_elementwise_fma(qe2, kk, qr[kw]);
                f32x2 p;
                p.x = __builtin_amdgcn_exp2f(sc.x);
                p.y = __builtin_amdgcn_exp2f(sc.y);
                l2 += p;
                a2 = __builtin_elementwise_fma(p, vv, a2);
            }
        }
    }
    float r0, r1;
    asm("v_rcp_f32 %0, %1" : "=v"(r0) : "v"(l2.x));
    asm("v_rcp_f32 %0, %1" : "=v"(r1) : "v"(l2.y));
    float2 ov = make_float2(a2.x * r0, a2.y * r1);
    *(float2*)(out + (size_t)bo * S + h * WW + w0) = ov;
}

extern "C" void kernel_launch(void* const* d_in, const int* in_sizes, int n_in,
                              void* d_out, int out_size, void* d_ws, size_t ws_size,
                              hipStream_t stream) {
    const float* x     = (const float*)d_in[0];
    const float* wq    = (const float*)d_in[1];
    const float* wk    = (const float*)d_in[2];
    const float* wv    = (const float*)d_in[3];
    const float* rel_h = (const float*)d_in[4];
    const float* rel_w = (const float*)d_in[5];
    float* out  = (float*)d_out;

    float* kbuf = (float*)d_ws;                             // [B][O][S] f32
    float* vbuf = kbuf + (size_t)BSZ * COUT * S;            // [B][O][S] f32

    dim3 gg(S / 64, COUT / 128, BSZ * 3);                   // (36,2,6)
    qkv_mfma<<<gg, 256, 0, stream>>>(x, wq, wk, wv, out, kbuf, vbuf);

    dim3 g2(HH / 16, BSZ * COUT);                           // (3,512)
    attn_win<<<g2, 384, 0, stream>>>(out, kbuf, vbuf, rel_h, rel_w, out);
}

// Round 12
// 32.958 us; speedup vs baseline: 1.8427x; 1.0594x over previous
//
#include <hip/hip_runtime.h>

#define CIN  256
#define COUT 256
#define BSZ  2
#define HH   48
#define WW   48
#define S    (HH * WW)   // 2304
#define KWIN 7

typedef short  short8 __attribute__((ext_vector_type(8)));
typedef float  f32x4  __attribute__((ext_vector_type(4)));
typedef float  f32x2  __attribute__((ext_vector_type(2)));

__device__ inline unsigned cvt_pk_bf16(float f0, float f1) {
    unsigned r;
    asm("v_cvt_pk_bf16_f32 %0, %1, %2" : "=v"(r) : "v"(f0), "v"(f1));
    return r;   // low16 = bf16(f0), high16 = bf16(f1), RNE
}

// ---------- MFMA QKV: D[s][o] = sum_c X[c][s] * W[o][c], pure bf16 ----------
// Identical compute to the 34.9 us round. Only change: k/v maps are stored as
// bf16 (packed cvt_pk + uint2 stores) -> half the intermediate-map traffic.
// q still f32 into d_out (it is overwritten by attn's output).
__global__ __launch_bounds__(256) void qkv_mfma(
    const float* __restrict__ x,              // [B][C][S]
    const float* __restrict__ wq, const float* __restrict__ wk, const float* __restrict__ wv,
    float* __restrict__ qout,                 // [B][O][S] f32 (d_out)
    unsigned short* __restrict__ kout,        // [B][O][S] bf16 (ws)
    unsigned short* __restrict__ vout)        // [B][O][S] bf16 (ws)
{
    __shared__ __align__(16) short Ahi[32][64][8];   // [c8][s][e] 32 KB
    const int t    = threadIdx.x;
    const int lane = t & 63;
    const int wid  = t >> 6;
    const int r16  = lane & 15;
    const int kq   = lane >> 4;
    const int s0   = blockIdx.x * 64;
    const int o0   = blockIdx.y * 128 + wid * 32;
    const int bm   = blockIdx.z;         // b*3 + m
    const int b    = bm / 3, m = bm % 3;
    const float* wmat = (m == 0) ? wq : (m == 1 ? wk : wv);
    float*          outf = qout + (size_t)b * COUT * S;
    unsigned short* outh = ((m == 1) ? kout : vout) + (size_t)b * COUT * S;
    const float* xb = x + (size_t)b * CIN * S + s0;

    const int ss = t & 63;
    const int cg = t >> 6;
#pragma unroll 2
    for (int p = 0; p < 8; ++p) {
        const int c8 = cg + p * 4;                   // 0..31
        const float* px = xb + (size_t)(c8 * 8) * S + ss;
        float f[8];
#pragma unroll
        for (int e = 0; e < 8; ++e) f[e] = px[(size_t)e * S];
        union { unsigned u[4]; short8 v; } H;
#pragma unroll
        for (int pp = 0; pp < 4; ++pp)
            H.u[pp] = cvt_pk_bf16(f[2 * pp], f[2 * pp + 1]);
        *(short8*)&Ahi[c8][ss][0] = H.v;
    }
    __syncthreads();

    f32x4 acc[4][2] = {};
#pragma unroll 2
    for (int kb = 0; kb < 8; ++kb) {
        const int c8 = kb * 4 + kq;
        short8 ah[4], bh[2];
#pragma unroll
        for (int i = 0; i < 4; ++i)
            ah[i] = *(const short8*)&Ahi[c8][i * 16 + r16][0];
#pragma unroll
        for (int j = 0; j < 2; ++j) {
            const float* pw = wmat + (size_t)(o0 + j * 16 + r16) * CIN + kb * 32 + kq * 8;
            const float4 wa = *(const float4*)pw;
            const float4 wb = *(const float4*)(pw + 4);
            union { unsigned u[4]; short8 v; } B;
            B.u[0] = cvt_pk_bf16(wa.x, wa.y);
            B.u[1] = cvt_pk_bf16(wa.z, wa.w);
            B.u[2] = cvt_pk_bf16(wb.x, wb.y);
            B.u[3] = cvt_pk_bf16(wb.z, wb.w);
            bh[j] = B.v;
        }
#pragma unroll
        for (int i = 0; i < 4; ++i)
#pragma unroll
            for (int j = 0; j < 2; ++j)
                acc[i][j] = __builtin_amdgcn_mfma_f32_16x16x32_bf16(ah[i], bh[j], acc[i][j], 0, 0, 0);
    }
    if (m == 0) {
#pragma unroll
        for (int i = 0; i < 4; ++i)
#pragma unroll
            for (int j = 0; j < 2; ++j) {
                const int o = o0 + j * 16 + r16;
                const int s = s0 + i * 16 + kq * 4;
                float4 r = make_float4(acc[i][j][0], acc[i][j][1], acc[i][j][2], acc[i][j][3]);
                *(float4*)(outf + (size_t)o * S + s) = r;
            }
    } else {
#pragma unroll
        for (int i = 0; i < 4; ++i)
#pragma unroll
            for (int j = 0; j < 2; ++j) {
                const int o = o0 + j * 16 + r16;
                const int s = s0 + i * 16 + kq * 4;
                uint2 pk;
                pk.x = cvt_pk_bf16(acc[i][j][0], acc[i][j][1]);
                pk.y = cvt_pk_bf16(acc[i][j][2], acc[i][j][3]);
                *(uint2*)(outh + (size_t)o * S + s) = pk;   // 8B aligned: s%4==0
            }
    }
}

// ---------------- Phase 2: windowed softmax-attention ----------------
// Byte-identical structure/inner loop to the 34.9 us round (16-row blocks,
// 384 thr, 2 outputs/thread, float2 LDS reads, packed fma, exp2). Only change:
// k/v maps arrive as bf16; staging converts with one shift per element.
__global__ __launch_bounds__(384) void attn_win(
    const float* __restrict__ qmap,            // [B*O][S] f32 (lives in d_out)
    const unsigned short* __restrict__ kmap,   // [B*O][S] bf16
    const unsigned short* __restrict__ vmap,   // [B*O][S] bf16
    const float* __restrict__ rel_h,
    const float* __restrict__ rel_w,
    float* __restrict__ out)                   // same buffer as qmap
{
    __shared__ __align__(16) float Ks[22][60];
    __shared__ __align__(16) float Vs[22][60];
    const int t  = threadIdx.x;
    const int h0 = blockIdx.x * 16;
    const int bo = blockIdx.y;
    const int o  = bo & 255;
    const unsigned short* kp = kmap + (size_t)bo * S;
    const unsigned short* vp = vmap + (size_t)bo * S;

    // stage rows h0-3..h0+18, cols -3..52 (col = w+3); zeros outside plane
    for (int i = t; i < 22 * 56; i += 384) {
        const int row = i / 56, col = i - row * 56;
        const int hh = h0 - 3 + row, ww = col - 3;
        const bool ok = ((unsigned)hh < (unsigned)HH) && ((unsigned)ww < (unsigned)WW);
        const int idx = hh * WW + ww;
        Ks[row][col] = ok ? __uint_as_float((unsigned)kp[idx] << 16) : 0.f;
        Vs[row][col] = ok ? __uint_as_float((unsigned)vp[idx] << 16) : 0.f;
    }

    const int w0 = (t % 24) * 2;     // outputs w0, w0+1
    const int r  = t / 24;           // 0..15
    const int h  = h0 + r;
    const float2 q2 = *(const float2*)(qmap + (size_t)bo * S + h * WW + w0);
    const float qe0 = q2.x * 1.44269504088896340736f;
    const float qe1 = q2.y * 1.44269504088896340736f;
    const f32x2 qe2 = {qe0, qe1};
    const bool ish = (o < 128);
    const float* rp = ish ? (rel_h + o * 7) : (rel_w + (o - 128) * 7);
    f32x2 qr[7];
#pragma unroll
    for (int i = 0; i < 7; ++i) {
        const float rv = rp[i];
        qr[i] = (f32x2){qe0 * rv, qe1 * rv};
    }

    __syncthreads();

    f32x2 l2 = {0.f, 0.f}, a2 = {0.f, 0.f};
#pragma unroll
    for (int kh = 0; kh < KWIN; ++kh) {
        const int rr = r + kh;
        float k8[8], v8[8];
#pragma unroll
        for (int n = 0; n < 4; ++n) {
            *(float2*)&k8[2 * n] = *(const float2*)&Ks[rr][w0 + 2 * n];
            *(float2*)&v8[2 * n] = *(const float2*)&Vs[rr][w0 + 2 * n];
        }
        if (ish) {
            const f32x2 b2 = qr[kh];
#pragma unroll
            for (int kw = 0; kw < KWIN; ++kw) {
                const f32x2 kk = {k8[kw], k8[kw + 1]};
                const f32x2 vv = {v8[kw], v8[kw + 1]};
                const f32x2 sc = __builtin_elementwise_fma(qe2, kk, b2);
                f32x2 p;
                p.x = __builtin_amdgcn_exp2f(sc.x);
                p.y = __builtin_amdgcn_exp2f(sc.y);
                l2 += p;
                a2 = __builtin_elementwise_fma(p, vv, a2);
            }
        } else {
#pragma unroll
            for (int kw = 0; kw < KWIN; ++kw) {
                const f32x2 kk = {k8[kw], k8[kw + 1]};
                const f32x2 vv = {v8[kw], v8[kw + 1]};
                const f32x2 sc = __builtin_elementwise_fma(qe2, kk, qr[kw]);
                f32x2 p;
                p.x = __builtin_amdgcn_exp2f(sc.x);
                p.y = __builtin_amdgcn_exp2f(sc.y);
                l2 += p;
                a2 = __builtin_elementwise_fma(p, vv, a2);
            }
        }
    }
    float r0, r1;
    asm("v_rcp_f32 %0, %1" : "=v"(r0) : "v"(l2.x));
    asm("v_rcp_f32 %0, %1" : "=v"(r1) : "v"(l2.y));
    float2 ov = make_float2(a2.x * r0, a2.y * r1);
    *(float2*)(out + (size_t)bo * S + h * WW + w0) = ov;
}

extern "C" void kernel_launch(void* const* d_in, const int* in_sizes, int n_in,
                              void* d_out, int out_size, void* d_ws, size_t ws_size,
                              hipStream_t stream) {
    const float* x     = (const float*)d_in[0];
    const float* wq    = (const float*)d_in[1];
    const float* wk    = (const float*)d_in[2];
    const float* wv    = (const float*)d_in[3];
    const float* rel_h = (const float*)d_in[4];
    const float* rel_w = (const float*)d_in[5];
    float* out = (float*)d_out;

    unsigned short* kbuf = (unsigned short*)d_ws;           // [B][O][S] bf16
    unsigned short* vbuf = kbuf + (size_t)BSZ * COUT * S;   // [B][O][S] bf16

    dim3 gg(S / 64, COUT / 128, BSZ * 3);                   // (36,2,6)
    qkv_mfma<<<gg, 256, 0, stream>>>(x, wq, wk, wv, out, kbuf, vbuf);

    dim3 g2(HH / 16, BSZ * COUT);                           // (3,512)
    attn_win<<<g2, 384, 0, stream>>>(out, kbuf, vbuf, rel_h, rel_w, out);
}

// Round 14
// 31.854 us; speedup vs baseline: 1.9065x; 1.0347x over previous
//
#include <hip/hip_runtime.h>

#define CIN  256
#define COUT 256
#define BSZ  2
#define HH   48
#define WW   48
#define S    (HH * WW)   // 2304
#define KWIN 7

typedef short  short8 __attribute__((ext_vector_type(8)));
typedef float  f32x4  __attribute__((ext_vector_type(4)));
typedef float  f32x2  __attribute__((ext_vector_type(2)));
typedef __fp16 h16x2  __attribute__((ext_vector_type(2)));

__device__ inline unsigned cvt_pk_bf16(float f0, float f1) {
    unsigned r;
    asm("v_cvt_pk_bf16_f32 %0, %1, %2" : "=v"(r) : "v"(f0), "v"(f1));
    return r;   // low16 = bf16(f0), high16 = bf16(f1), RNE
}

__device__ inline unsigned cvt_pkrtz_f16(float f0, float f1) {
    union { h16x2 h; unsigned u; } c;
    c.h = __builtin_amdgcn_cvt_pkrtz(f0, f1);   // low16 = f16(f0), high16 = f16(f1), RTZ
    return c.u;
}

__device__ inline float f16_to_f32(unsigned short u) {
    union { unsigned short u; __fp16 h; } c; c.u = u;
    return (float)c.h;
}

// ---------- MFMA QKV: D[s][o] = sum_c X[c][s] * W[o][c], pure bf16 compute ----------
// Identical compute to the 32.9 us round. Maps are now stored as fp16 (RTZ pack):
// q pre-scaled by log2e into ws (d_out is no longer an input of attn), k/v fp16
// (more precise than r12's bf16: 2^-10 vs 2^-9). Same byte traffic for k/v,
// half for q.
__global__ __launch_bounds__(256) void qkv_mfma(
    const float* __restrict__ x,              // [B][C][S]
    const float* __restrict__ wq, const float* __restrict__ wk, const float* __restrict__ wv,
    unsigned short* __restrict__ qout,        // [B][O][S] f16 * log2e (ws)
    unsigned short* __restrict__ kout,        // [B][O][S] f16 (ws)
    unsigned short* __restrict__ vout)        // [B][O][S] f16 (ws)
{
    __shared__ __align__(16) short Ahi[32][64][8];   // [c8][s][e] 32 KB
    const int t    = threadIdx.x;
    const int lane = t & 63;
    const int wid  = t >> 6;
    const int r16  = lane & 15;
    const int kq   = lane >> 4;
    const int s0   = blockIdx.x * 64;
    const int o0   = blockIdx.y * 128 + wid * 32;
    const int bm   = blockIdx.z;         // b*3 + m
    const int b    = bm / 3, m = bm % 3;
    const float* wmat = (m == 0) ? wq : (m == 1 ? wk : wv);
    unsigned short* outh = ((m == 0) ? qout : (m == 1 ? kout : vout)) + (size_t)b * COUT * S;
    const float* xb = x + (size_t)b * CIN * S + s0;

    const int ss = t & 63;
    const int cg = t >> 6;
#pragma unroll 2
    for (int p = 0; p < 8; ++p) {
        const int c8 = cg + p * 4;                   // 0..31
        const float* px = xb + (size_t)(c8 * 8) * S + ss;
        float f[8];
#pragma unroll
        for (int e = 0; e < 8; ++e) f[e] = px[(size_t)e * S];
        union { unsigned u[4]; short8 v; } H;
#pragma unroll
        for (int pp = 0; pp < 4; ++pp)
            H.u[pp] = cvt_pk_bf16(f[2 * pp], f[2 * pp + 1]);
        *(short8*)&Ahi[c8][ss][0] = H.v;
    }
    __syncthreads();

    f32x4 acc[4][2] = {};
#pragma unroll 2
    for (int kb = 0; kb < 8; ++kb) {
        const int c8 = kb * 4 + kq;
        short8 ah[4], bh[2];
#pragma unroll
        for (int i = 0; i < 4; ++i)
            ah[i] = *(const short8*)&Ahi[c8][i * 16 + r16][0];
#pragma unroll
        for (int j = 0; j < 2; ++j) {
            const float* pw = wmat + (size_t)(o0 + j * 16 + r16) * CIN + kb * 32 + kq * 8;
            const float4 wa = *(const float4*)pw;
            const float4 wb = *(const float4*)(pw + 4);
            union { unsigned u[4]; short8 v; } B;
            B.u[0] = cvt_pk_bf16(wa.x, wa.y);
            B.u[1] = cvt_pk_bf16(wa.z, wa.w);
            B.u[2] = cvt_pk_bf16(wb.x, wb.y);
            B.u[3] = cvt_pk_bf16(wb.z, wb.w);
            bh[j] = B.v;
        }
#pragma unroll
        for (int i = 0; i < 4; ++i)
#pragma unroll
            for (int j = 0; j < 2; ++j)
                acc[i][j] = __builtin_amdgcn_mfma_f32_16x16x32_bf16(ah[i], bh[j], acc[i][j], 0, 0, 0);
    }
    const float sc = (m == 0) ? 1.44269504088896340736f : 1.0f;
#pragma unroll
    for (int i = 0; i < 4; ++i)      // s subtile
#pragma unroll
        for (int j = 0; j < 2; ++j) { // o subtile
            const int o = o0 + j * 16 + r16;
            const int s = s0 + i * 16 + kq * 4;
            uint2 pk;
            pk.x = cvt_pkrtz_f16(acc[i][j][0] * sc, acc[i][j][1] * sc);
            pk.y = cvt_pkrtz_f16(acc[i][j][2] * sc, acc[i][j][3] * sc);
            *(uint2*)(outh + (size_t)o * S + s) = pk;   // 8B aligned: s%4==0
        }
}

// ---------------- Phase 2: windowed softmax-attention ----------------
// Byte-identical structure/inner loop to the 32.9 us round (16-row blocks,
// 384 thr, 2 outputs/thread, float2 LDS reads, packed fma, exp2). Maps arrive
// as fp16; staging converts with one v_cvt_f32_f16 per element. q arrives
// pre-scaled by log2e. Output written to d_out (f32).
__global__ __launch_bounds__(384) void attn_win(
    const unsigned short* __restrict__ qmap,   // [B*O][S] f16 (pre-scaled log2e)
    const unsigned short* __restrict__ kmap,   // [B*O][S] f16
    const unsigned short* __restrict__ vmap,   // [B*O][S] f16
    const float* __restrict__ rel_h,
    const float* __restrict__ rel_w,
    float* __restrict__ out)                   // [B*O][S] f32 (d_out)
{
    __shared__ __align__(16) float Ks[22][60];
    __shared__ __align__(16) float Vs[22][60];
    const int t  = threadIdx.x;
    const int h0 = blockIdx.x * 16;
    const int bo = blockIdx.y;
    const int o  = bo & 255;
    const unsigned short* kp = kmap + (size_t)bo * S;
    const unsigned short* vp = vmap + (size_t)bo * S;

    // stage rows h0-3..h0+18, cols -3..52 (col = w+3); zeros outside plane
    for (int i = t; i < 22 * 56; i += 384) {
        const int row = i / 56, col = i - row * 56;
        const int hh = h0 - 3 + row, ww = col - 3;
        const bool ok = ((unsigned)hh < (unsigned)HH) && ((unsigned)ww < (unsigned)WW);
        const int idx = hh * WW + ww;
        Ks[row][col] = ok ? f16_to_f32(kp[idx]) : 0.f;
        Vs[row][col] = ok ? f16_to_f32(vp[idx]) : 0.f;
    }

    const int w0 = (t % 24) * 2;     // outputs w0, w0+1
    const int r  = t / 24;           // 0..15
    const int h  = h0 + r;
    union { unsigned u; unsigned short s[2]; } qu;
    qu.u = *(const unsigned*)(qmap + (size_t)bo * S + h * WW + w0);
    const float qe0 = f16_to_f32(qu.s[0]);   // already * log2e
    const float qe1 = f16_to_f32(qu.s[1]);
    const f32x2 qe2 = {qe0, qe1};
    const bool ish = (o < 128);
    const float* rp = ish ? (rel_h + o * 7) : (rel_w + (o - 128) * 7);
    f32x2 qr[7];
#pragma unroll
    for (int i = 0; i < 7; ++i) {
        const float rv = rp[i];
        qr[i] = (f32x2){qe0 * rv, qe1 * rv};
    }

    __syncthreads();

    f32x2 l2 = {0.f, 0.f}, a2 = {0.f, 0.f};
#pragma unroll
    for (int kh = 0; kh < KWIN; ++kh) {
        const int rr = r + kh;
        float k8[8], v8[8];
#pragma unroll
        for (int n = 0; n < 4; ++n) {
            *(float2*)&k8[2 * n] = *(const float2*)&Ks[rr][w0 + 2 * n];
            *(float2*)&v8[2 * n] = *(const float2*)&Vs[rr][w0 + 2 * n];
        }
        if (ish) {
            const f32x2 b2 = qr[kh];
#pragma unroll
            for (int kw = 0; kw < KWIN; ++kw) {
                const f32x2 kk = {k8[kw], k8[kw + 1]};
                const f32x2 vv = {v8[kw], v8[kw + 1]};
                const f32x2 sc = __builtin_elementwise_fma(qe2, kk, b2);
                f32x2 p;
                p.x = __builtin_amdgcn_exp2f(sc.x);
                p.y = __builtin_amdgcn_exp2f(sc.y);
                l2 += p;
                a2 = __builtin_elementwise_fma(p, vv, a2);
            }
        } else {
#pragma unroll
            for (int kw = 0; kw < KWIN; ++kw) {
                const f32x2 kk = {k8[kw], k8[kw + 1]};
                const f32x2 vv = {v8[kw], v8[kw + 1]};
                const f32x2 sc = __builtin_elementwise_fma(qe2, kk, qr[kw]);
                f32x2 p;
                p.x = __builtin_amdgcn_exp2f(sc.x);
                p.y = __builtin_amdgcn_exp2f(sc.y);
                l2 += p;
                a2 = __builtin_elementwise_fma(p, vv, a2);
            }
        }
    }
    float r0, r1;
    asm("v_rcp_f32 %0, %1" : "=v"(r0) : "v"(l2.x));
    asm("v_rcp_f32 %0, %1" : "=v"(r1) : "v"(l2.y));
    float2 ov = make_float2(a2.x * r0, a2.y * r1);
    *(float2*)(out + (size_t)bo * S + h * WW + w0) = ov;
}

extern "C" void kernel_launch(void* const* d_in, const int* in_sizes, int n_in,
                              void* d_out, int out_size, void* d_ws, size_t ws_size,
                              hipStream_t stream) {
    const float* x     = (const float*)d_in[0];
    const float* wq    = (const float*)d_in[1];
    const float* wk    = (const float*)d_in[2];
    const float* wv    = (const float*)d_in[3];
    const float* rel_h = (const float*)d_in[4];
    const float* rel_w = (const float*)d_in[5];
    float* out = (float*)d_out;

    const size_t N = (size_t)BSZ * COUT * S;
    unsigned short* qbuf = (unsigned short*)d_ws;           // [B][O][S] f16*log2e
    unsigned short* kbuf = qbuf + N;                        // [B][O][S] f16
    unsigned short* vbuf = kbuf + N;                        // [B][O][S] f16

    dim3 gg(S / 64, COUT / 128, BSZ * 3);                   // (36,2,6)
    qkv_mfma<<<gg, 256, 0, stream>>>(x, wq, wk, wv, qbuf, kbuf, vbuf);

    dim3 g2(HH / 16, BSZ * COUT);                           // (3,512)
    attn_win<<<g2, 384, 0, stream>>>(qbuf, kbuf, vbuf, rel_h, rel_w, out);
}